// Round 18
// baseline (1147.354 us; speedup 1.0000x reference)
//
#include <hip/hip_runtime.h>
#include <math.h>

#define NB 4
#define NH 128
#define NW 128
#define TH 256
#define TW 256
#define K0 96            // layer0 K padded 84->96 (zeros)
#define MROWS 128        // rows per block = 32 px * 4 ensembles
#define PIXB 32          // pixels per block
#define SST 104          // stage row stride (f16) for phase-0 buffer

typedef _Float16 f16;
typedef f16  f16x8 __attribute__((ext_vector_type(8)));
typedef f16  f16x4v __attribute__((ext_vector_type(4)));
typedef __fp16 fp16x2 __attribute__((ext_vector_type(2)));
typedef float f32x4 __attribute__((ext_vector_type(4)));
typedef float f32x16 __attribute__((ext_vector_type(16)));

// ws layout (f16): W0t[256][96] | W1t[256][256] | W2t[256][256] | W3t[16][256] |
//                  peY[256][8] | peX[256][8] | ft[B][H][W][64]
#define OFF_W1 24576
#define OFF_W2 (OFF_W1 + 65536)
#define OFF_W3 (OFF_W2 + 65536)
#define OFF_PE (OFF_W3 + 4096)
#define WS_W_ELEMS (OFF_PE + 4096)
#define FT_ELEMS (NB * NH * NW * 64)

// act: row-major [128][256] f16 (512 B rows), full-width XOR swizzle.
__device__ __forceinline__ int act_off(int row, int colByte) {
  return row * 512 + (colByte ^ ((row & 31) << 4));
}

__global__ void cvt_weights(const float* __restrict__ w0, const float* __restrict__ w1,
                            const float* __restrict__ w2, const float* __restrict__ w3,
                            f16* __restrict__ ws) {
  const int i = blockIdx.x * 256 + threadIdx.x;
  if (i < 24576) {                       // W0t[n][k] = w0[k][n], k<84 else 0
    const int n = i / 96, k = i - n * 96;
    ws[i] = (k < 84) ? (f16)w0[k * 256 + n] : (f16)0.f;
  } else if (i < OFF_W2) {               // W1t[n][k] = w1[k][n]
    const int j = i - OFF_W1; const int n = j >> 8, k = j & 255;
    ws[i] = (f16)w1[k * 256 + n];
  } else if (i < OFF_W3) {               // W2t
    const int j = i - OFF_W2; const int n = j >> 8, k = j & 255;
    ws[i] = (f16)w2[k * 256 + n];
  } else if (i < OFF_PE) {               // W3t[n][k] = w3[k][n], n<3 else 0
    const int j = i - OFF_W3; const int n = j >> 8, k = j & 255;
    ws[i] = (n < 3) ? (f16)w3[k * 3 + n] : (f16)0.f;
  } else if (i < WS_W_ELEMS) {           // pos-enc tables
    const int j = i - OFF_PE;            // [0,2048): peY, [2048,4096): peX
    const int o = (j & 2047) >> 3, e = j & 7;
    const float c = (2.0f * o + 1.0f) / 256.0f - 1.0f;
    const float f = (float)(1 << (e & 3)) * (float)M_PI;
    ws[i] = (f16)((e < 4) ? sinf(c * f) : cosf(c * f));
  }
}

// feat f32 [B][64][H][W] -> ft f16 [B][H][W][64]
__global__ void transpose_feat(const float* __restrict__ feat, f16* __restrict__ ft) {
  __shared__ f16 tile[64][66];
  const int bid = blockIdx.x;
  const int xt = bid & 1, y = (bid >> 1) & 127, b = bid >> 8;
  const int x0 = xt * 64;
  {
    const int c4 = threadIdx.x >> 6, x = threadIdx.x & 63;
#pragma unroll
    for (int co = 0; co < 16; ++co) {
      const int c = co * 4 + c4;
      tile[x][c] = (f16)feat[((size_t)(b * 64 + c) * NH + y) * NW + x0 + x];
    }
  }
  __syncthreads();
  {
    const int x4 = threadIdx.x >> 6, c = threadIdx.x & 63;
#pragma unroll
    for (int xo = 0; xo < 16; ++xo) {
      const int x = xo * 4 + x4;
      ft[((size_t)(b * NH + y) * NW + x0 + x) * 64 + c] = tile[x][c];
    }
  }
}

// relu + pack two f32 -> one dword of 2 f16 (RTZ; elem0 = first arg)
__device__ __forceinline__ int pk(float a, float b) {
  fp16x2 h = __builtin_amdgcn_cvt_pkrtz(fmaxf(a, 0.f), fmaxf(b, 0.f));
  return __builtin_bit_cast(int, h);
}

// D(acc) -> next-layer B fragments, in registers via shfl_xor(32) + select.
// acc[nt][r]: n = nt*32 + (r&3)+8*(r>>2)+4*hi, m = l&31 (verified layout).
// B frag ks: lane holds k = ks*16 + hi*8 + j. Block nt covers frags 2nt,2nt+1.
// Per quad: lo lane keeps X=(own low-quad) and takes partner X for j=4..7;
// hi lane takes partner Y for j=0..3 and keeps own Y.
__device__ __forceinline__ void transition(const f32x16* acc, f16x8* Bn, bool hiL) {
#pragma unroll
  for (int nt = 0; nt < 8; ++nt) {
    const f32x16 a = acc[nt];
    int X0 = pk(a[0], a[1]),  X1 = pk(a[2], a[3]);
    int Y0 = pk(a[4], a[5]),  Y1 = pk(a[6], a[7]);
    int pX0 = __shfl_xor(X0, 32), pX1 = __shfl_xor(X1, 32);
    int pY0 = __shfl_xor(Y0, 32), pY1 = __shfl_xor(Y1, 32);
    int4 q0;
    q0.x = hiL ? pY0 : X0;
    q0.y = hiL ? pY1 : X1;
    q0.z = hiL ? Y0 : pX0;
    q0.w = hiL ? Y1 : pX1;
    Bn[2 * nt] = __builtin_bit_cast(f16x8, q0);
    int X2 = pk(a[8], a[9]),   X3 = pk(a[10], a[11]);
    int Y2 = pk(a[12], a[13]), Y3 = pk(a[14], a[15]);
    int pX2 = __shfl_xor(X2, 32), pX3 = __shfl_xor(X3, 32);
    int pY2 = __shfl_xor(Y2, 32), pY3 = __shfl_xor(Y3, 32);
    int4 q1;
    q1.x = hiL ? pY2 : X2;
    q1.y = hiL ? pY3 : X3;
    q1.z = hiL ? Y2 : pX2;
    q1.w = hiL ? Y3 : pX3;
    Bn[2 * nt + 1] = __builtin_bit_cast(f16x8, q1);
  }
}

// One 256-wide layer, ALL-REGISTER: B (act rows) in VGPRs, W streamed from
// L2 (dbuf 4-frag halves), acc[8] f32x16. No LDS, no barriers, no asm waits.
template<int K>
__device__ __forceinline__ void dense_reg(const f16* __restrict__ Wt,
                                          const float* __restrict__ bias,
                                          const f16x8* Bf, f32x16* acc, int l) {
  constexpr int NK = K / 16;
  const int lo = l & 31, hi = l >> 5;
#pragma unroll
  for (int nt = 0; nt < 8; ++nt) {
    f32x16 ci;
#pragma unroll
    for (int g = 0; g < 4; ++g) {
      const float4 b4 = *(const float4*)(bias + nt * 32 + 8 * g + 4 * hi);
      ci[4 * g + 0] = b4.x; ci[4 * g + 1] = b4.y; ci[4 * g + 2] = b4.z; ci[4 * g + 3] = b4.w;
    }
    acc[nt] = ci;
  }
  const f16* wsrc = Wt + (size_t)lo * K + hi * 8;
  f16x8 Wr0[4], Wr1[4];
#pragma unroll
  for (int i = 0; i < 4; ++i) Wr0[i] = *(const f16x8*)(wsrc + (size_t)i * 32 * K);
#pragma unroll
  for (int ks = 0; ks < NK; ++ks) {
#pragma unroll
    for (int i = 0; i < 4; ++i)
      Wr1[i] = *(const f16x8*)(wsrc + (size_t)(4 + i) * 32 * K + ks * 16);
    __builtin_amdgcn_s_setprio(1);
#pragma unroll
    for (int i = 0; i < 4; ++i)
      acc[i] = __builtin_amdgcn_mfma_f32_32x32x16_f16(Wr0[i], Bf[ks], acc[i], 0, 0, 0);
    __builtin_amdgcn_s_setprio(0);
    if (ks + 1 < NK) {
#pragma unroll
      for (int i = 0; i < 4; ++i)
        Wr0[i] = *(const f16x8*)(wsrc + (size_t)i * 32 * K + (ks + 1) * 16);
    }
    __builtin_amdgcn_s_setprio(1);
#pragma unroll
    for (int i = 0; i < 4; ++i)
      acc[4 + i] = __builtin_amdgcn_mfma_f32_32x32x16_f16(Wr1[i], Bf[ks], acc[4 + i], 0, 0, 0);
    __builtin_amdgcn_s_setprio(0);
  }
}

template<bool USE_FT>
__global__ __launch_bounds__(256, 2) void inr2d_mfma(
    const float* __restrict__ feat, const f16* __restrict__ ft,
    const float* __restrict__ b0, const float* __restrict__ b1,
    const float* __restrict__ b2, const float* __restrict__ b3,
    const f16* __restrict__ ws, float* __restrict__ out)
{
  __shared__ f16 act[MROWS * 256];     // 64 KB; first 26.6 KB aliased as stage
  __shared__ f16 pred_s[MROWS][4];     // 1 KB

  char* actc = (char*)act;
  f16* stage = act;                    // [128][SST] f16, consumed before act written
  const int t = threadIdx.x;
  const int blk = ((blockIdx.x & 7) << 10) | (blockIdx.x >> 3);  // 8192 bijective

  // ---------- phase 0: build 128 input rows into stage (2 thr/row) ----------
  {
    const int r = t >> 1, sub = t & 1;
    const int pix = r >> 2, e = r & 3;
    const int gp = blk * PIXB + pix;
    const int b = gp >> 16, rem = gp & 65535;
    const int oy = rem >> 8, ox = rem & 255;

    const float cy = (2.0f * oy + 1.0f) / (float)TH - 1.0f;
    const float cx = (2.0f * ox + 1.0f) / (float)TW - 1.0f;
    const float vx = (e & 2) ? 1.0f : -1.0f;
    const float vy = (e & 1) ? 1.0f : -1.0f;
    const float rr = 1.0f / (float)NH;

    float c0 = fminf(fmaxf(cy + vx * rr + 1e-6f, -1.0f + 1e-6f), 1.0f - 1e-6f);
    float c1 = fminf(fmaxf(cx + vy * rr + 1e-6f, -1.0f + 1e-6f), 1.0f - 1e-6f);

    const float ix = (c1 + 1.0f) * 0.5f * (float)(NW - 1);
    const float iy = (c0 + 1.0f) * 0.5f * (float)(NH - 1);
    const float x0f = floorf(ix), y0f = floorf(iy);
    int x0 = (int)x0f; x0 = max(0, min(x0, NW - 1));
    int x1 = min(x0 + 1, NW - 1);
    int y0 = (int)y0f; y0 = max(0, min(y0, NH - 1));
    int y1 = min(y0 + 1, NH - 1);
    const float wx1 = ix - x0f, wx0 = 1.0f - wx1;
    const float wy1 = iy - y0f, wy0 = 1.0f - wy1;
    const float w00 = wy0 * wx0, w01 = wy0 * wx1, w10 = wy1 * wx0, w11 = wy1 * wx1;

    if (USE_FT) {
      const f16* fb = ft + (size_t)b * (NH * NW * 64);
      const f16* r00 = fb + (size_t)(y0 * NW + x0) * 64 + sub * 32;
      const f16* r01 = fb + (size_t)(y0 * NW + x1) * 64 + sub * 32;
      const f16* r10 = fb + (size_t)(y1 * NW + x0) * 64 + sub * 32;
      const f16* r11 = fb + (size_t)(y1 * NW + x1) * 64 + sub * 32;
#pragma unroll
      for (int h = 0; h < 4; ++h) {
        const f16x8 a00 = *(const f16x8*)(r00 + h * 8);
        const f16x8 a01 = *(const f16x8*)(r01 + h * 8);
        const f16x8 a10 = *(const f16x8*)(r10 + h * 8);
        const f16x8 a11 = *(const f16x8*)(r11 + h * 8);
        f16x8 o;
#pragma unroll
        for (int i = 0; i < 8; ++i)
          o[i] = (f16)(w00 * (float)a00[i] + w01 * (float)a01[i] +
                       w10 * (float)a10[i] + w11 * (float)a11[i]);
        *(f16x8*)(stage + r * SST + sub * 32 + h * 8) = o;
      }
    } else {
      const float* fb = feat + (size_t)b * 64 * NH * NW;
      const int i00 = y0 * NW + x0, i01 = y0 * NW + x1;
      const int i10 = y1 * NW + x0, i11 = y1 * NW + x1;
#pragma unroll
      for (int i = 0; i < 32; ++i) {
        const int c = sub * 32 + i;
        const float* fc = fb + (size_t)c * (NH * NW);
        stage[r * SST + c] = (f16)(w00 * fc[i00] + w01 * fc[i01] +
                                   w10 * fc[i10] + w11 * fc[i11]);
      }
    }
    if (sub == 0) {
      const float qy = -1.0f + 1.0f / NH + (2.0f / NH) * (wy0 * (float)y0 + wy1 * (float)y1);
      const float qx = -1.0f + 1.0f / NW + (2.0f / NW) * (wx0 * (float)x0 + wx1 * (float)x1);
      const float rely = (cy - qy) * (float)NH;
      const float relx = (cx - qx) * (float)NW;
      stage[r * SST + 64] = (f16)rely;
      stage[r * SST + 65] = (f16)relx;
      if (USE_FT) {
        const f16* py = ws + OFF_PE + (size_t)oy * 8;
        const f16* px = ws + OFF_PE + 2048 + (size_t)ox * 8;
#pragma unroll
        for (int j = 0; j < 8; ++j) {
          stage[r * SST + 66 + j] = py[j];
          stage[r * SST + 74 + j] = px[j];
        }
      } else {
#pragma unroll
        for (int ll = 0; ll < 4; ++ll) {
          const float f = (float)(1 << ll) * (float)M_PI;
          stage[r * SST + 66 + ll] = (f16)sinf(cy * f);
          stage[r * SST + 70 + ll] = (f16)cosf(cy * f);
          stage[r * SST + 74 + ll] = (f16)sinf(cx * f);
          stage[r * SST + 78 + ll] = (f16)cosf(cx * f);
        }
      }
      stage[r * SST + 82] = (f16)1.0f;   // rel_cell = 1.0
      stage[r * SST + 83] = (f16)1.0f;
#pragma unroll
      for (int z = 84; z < K0; ++z) stage[r * SST + z] = (f16)0.f;
    }
  }
  __syncthreads();

  const int w = t >> 6, l = t & 63;
  const int lo = l & 31, hi = l >> 5;
  const bool hiL = (hi != 0);

  // load layer-0 B fragments from stage (wave w owns rows w*32..w*32+31)
  f16x8 B0[6];
#pragma unroll
  for (int ks = 0; ks < 6; ++ks)
    B0[ks] = *(const f16x8*)(stage + (size_t)(w * 32 + lo) * SST + ks * 16 + hi * 8);
  __syncthreads();   // stage fully consumed -> act may be overwritten later

  f32x16 acc[8];
  f16x8 B1[16];

  dense_reg<K0 >(ws,          b0, B0, acc, l);
  transition(acc, B1, hiL);
  dense_reg<256>(ws + OFF_W1, b1, B1, acc, l);
  transition(acc, B1, hiL);
  dense_reg<256>(ws + OFF_W2, b2, B1, acc, l);

  // epilogue: relu + f16 -> act LDS in D-layout (row = w*32+lo, n = nt*32+8g+4hi)
#pragma unroll
  for (int nt = 0; nt < 8; ++nt)
#pragma unroll
    for (int g = 0; g < 4; ++g) {
      f16x4v o;
      o[0] = (f16)fmaxf(acc[nt][4 * g + 0], 0.f);
      o[1] = (f16)fmaxf(acc[nt][4 * g + 1], 0.f);
      o[2] = (f16)fmaxf(acc[nt][4 * g + 2], 0.f);
      o[3] = (f16)fmaxf(acc[nt][4 * g + 3], 0.f);
      *(f16x4v*)(actc + act_off(w * 32 + lo, nt * 64 + 16 * g + 8 * hi)) = o;
    }
  __syncthreads();

  // ---------- layer 3: 256 -> 3 (wave w: rows w*32 .. w*32+31) ----------
  {
    const int nl = l & 15, kq = l >> 4;
    const f16* Abase = ws + OFF_W3 + nl * 256 + kq * 8;
#pragma unroll
    for (int p = 0; p < 2; ++p) {
      const int row = w * 32 + p * 16 + nl;
      f32x4 a4 = {0.f, 0.f, 0.f, 0.f};
#pragma unroll
      for (int ks = 0; ks < 8; ++ks) {
        f16x8 a = *(const f16x8*)(Abase + ks * 32);
        f16x8 b = *(const f16x8*)(actc + act_off(row, 64 * ks + 16 * kq));
        a4 = __builtin_amdgcn_mfma_f32_16x16x32_f16(a, b, a4, 0, 0, 0);
      }
      if (l < 16) {
        f16x4v pr;
        pr[0] = (f16)(a4[0] + b3[0]); pr[1] = (f16)(a4[1] + b3[1]);
        pr[2] = (f16)(a4[2] + b3[2]); pr[3] = (f16)0.f;
        *(f16x4v*)(&pred_s[w * 32 + p * 16 + l][0]) = pr;
      }
    }
  }
  __syncthreads();

  // ---------- ensemble combine (areas recomputed analytically) ----------
  if (t < PIXB * 3) {
    const int pix = t / 3, o = t - pix * 3;
    const int gp = blk * PIXB + pix;
    const int b = gp >> 16, rem = gp & 65535;
    const int oy = rem >> 8, ox = rem & 255;
    const float cy = (2.0f * oy + 1.0f) / (float)TH - 1.0f;
    const float cx = (2.0f * ox + 1.0f) / (float)TW - 1.0f;
    const float rr = 1.0f / (float)NH;
    float ar[4];
#pragma unroll
    for (int e = 0; e < 4; ++e) {
      const float vx = (e & 2) ? 1.0f : -1.0f;
      const float vy = (e & 1) ? 1.0f : -1.0f;
      float c0 = fminf(fmaxf(cy + vx * rr + 1e-6f, -1.0f + 1e-6f), 1.0f - 1e-6f);
      float c1 = fminf(fmaxf(cx + vy * rr + 1e-6f, -1.0f + 1e-6f), 1.0f - 1e-6f);
      const float ix = (c1 + 1.0f) * 0.5f * (float)(NW - 1);
      const float iy = (c0 + 1.0f) * 0.5f * (float)(NH - 1);
      const float x0f = floorf(ix), y0f = floorf(iy);
      int x0 = (int)x0f; x0 = max(0, min(x0, NW - 1));
      int x1 = min(x0 + 1, NW - 1);
      int y0 = (int)y0f; y0 = max(0, min(y0, NH - 1));
      int y1 = min(y0 + 1, NH - 1);
      const float wx1 = ix - x0f, wx0 = 1.0f - wx1;
      const float wy1 = iy - y0f, wy0 = 1.0f - wy1;
      const float qy = -1.0f + 1.0f / NH + (2.0f / NH) * (wy0 * (float)y0 + wy1 * (float)y1);
      const float qx = -1.0f + 1.0f / NW + (2.0f / NW) * (wx0 * (float)x0 + wx1 * (float)x1);
      const float rely = (cy - qy) * (float)NH;
      const float relx = (cx - qx) * (float)NW;
      ar[e] = fabsf(rely * relx) + 1e-9f;
    }
    const int r0 = pix * 4;
    const float tot = ar[0] + ar[1] + ar[2] + ar[3];
    const float v = (float)pred_s[r0][o] * ar[3] + (float)pred_s[r0 + 1][o] * ar[2] +
                    (float)pred_s[r0 + 2][o] * ar[1] + (float)pred_s[r0 + 3][o] * ar[0];
    out[(((size_t)b * 3 + o) << 16) + (oy << 8) + ox] = v / tot;
  }
}

extern "C" void kernel_launch(void* const* d_in, const int* in_sizes, int n_in,
                              void* d_out, int out_size, void* d_ws, size_t ws_size,
                              hipStream_t stream) {
  const float* feat = (const float*)d_in[0];
  const float* w0 = (const float*)d_in[1];
  const float* b0 = (const float*)d_in[2];
  const float* w1 = (const float*)d_in[3];
  const float* b1 = (const float*)d_in[4];
  const float* w2 = (const float*)d_in[5];
  const float* b2 = (const float*)d_in[6];
  const float* w3 = (const float*)d_in[7];
  const float* b3 = (const float*)d_in[8];
  float* out = (float*)d_out;
  f16* ws = (f16*)d_ws;

  cvt_weights<<<(WS_W_ELEMS + 255) / 256, 256, 0, stream>>>(w0, w1, w2, w3, ws);

  const int blocks = (NB * TH * TW) / PIXB;  // 8192
  const bool use_ft = ws_size >= (size_t)(WS_W_ELEMS + FT_ELEMS) * sizeof(f16);
  if (use_ft) {
    f16* ft = ws + WS_W_ELEMS;
    transpose_feat<<<NB * NH * (NW / 64), 256, 0, stream>>>(feat, ft);
    inr2d_mfma<true><<<blocks, 256, 0, stream>>>(feat, ft, b0, b1, b2, b3, ws, out);
  } else {
    inr2d_mfma<false><<<blocks, 256, 0, stream>>>(feat, nullptr, b0, b1, b2, b3, ws, out);
  }
}

// Round 19
// 400.030 us; speedup vs baseline: 2.8682x; 2.8682x over previous
//
#include <hip/hip_runtime.h>
#include <math.h>

#define NB 4
#define NH 128
#define NW 128
#define TH 256
#define TW 256
#define K0 96            // layer0 K padded 84->96 (zeros)
#define MROWS 128        // rows per block = 32 px * 4 ensembles
#define PIXB 32          // pixels per block

typedef _Float16 f16;
typedef f16  f16x8 __attribute__((ext_vector_type(8)));
typedef f16  f16x4v __attribute__((ext_vector_type(4)));
typedef float f32x4 __attribute__((ext_vector_type(4)));
typedef float f32x16 __attribute__((ext_vector_type(16)));

// ws layout (f16): W0t[256][96] | W1t[256][256] | W2t[256][256] | W3t[16][256] |
//                  peY[256][8] | peX[256][8] | ft[B][H][W][64]
#define OFF_W1 24576
#define OFF_W2 (OFF_W1 + 65536)
#define OFF_W3 (OFF_W2 + 65536)
#define OFF_PE (OFF_W3 + 4096)
#define WS_W_ELEMS (OFF_PE + 4096)
#define FT_ELEMS (NB * NH * NW * 64)

// act: row-major [128][256] f16 (512 B rows), full-width XOR swizzle:
// byte = row*512 + (colByte ^ ((row&31)<<4)). Bijective per row, 16B-aligned.
__device__ __forceinline__ int act_off(int row, int colByte) {
  return row * 512 + (colByte ^ ((row & 31) << 4));
}

__global__ void cvt_weights(const float* __restrict__ w0, const float* __restrict__ w1,
                            const float* __restrict__ w2, const float* __restrict__ w3,
                            f16* __restrict__ ws) {
  const int i = blockIdx.x * 256 + threadIdx.x;
  if (i < 24576) {                       // W0t[n][k] = w0[k][n], k<84 else 0
    const int n = i / 96, k = i - n * 96;
    ws[i] = (k < 84) ? (f16)w0[k * 256 + n] : (f16)0.f;
  } else if (i < OFF_W2) {               // W1t[n][k] = w1[k][n]
    const int j = i - OFF_W1; const int n = j >> 8, k = j & 255;
    ws[i] = (f16)w1[k * 256 + n];
  } else if (i < OFF_W3) {               // W2t
    const int j = i - OFF_W2; const int n = j >> 8, k = j & 255;
    ws[i] = (f16)w2[k * 256 + n];
  } else if (i < OFF_PE) {               // W3t[n][k] = w3[k][n], n<3 else 0
    const int j = i - OFF_W3; const int n = j >> 8, k = j & 255;
    ws[i] = (n < 3) ? (f16)w3[k * 3 + n] : (f16)0.f;
  } else if (i < WS_W_ELEMS) {           // pos-enc tables
    const int j = i - OFF_PE;            // [0,2048): peY, [2048,4096): peX
    const int o = (j & 2047) >> 3, e = j & 7;
    const float c = (2.0f * o + 1.0f) / 256.0f - 1.0f;
    const float f = (float)(1 << (e & 3)) * (float)M_PI;
    ws[i] = (f16)((e < 4) ? sinf(c * f) : cosf(c * f));
  }
}

// feat f32 [B][64][H][W] -> ft f16 [B][H][W][64]
__global__ void transpose_feat(const float* __restrict__ feat, f16* __restrict__ ft) {
  __shared__ f16 tile[64][66];
  const int bid = blockIdx.x;                 // 1024 blocks
  const int xt = bid & 1, y = (bid >> 1) & 127, b = bid >> 8;
  const int x0 = xt * 64;
  {
    const int c4 = threadIdx.x >> 6, x = threadIdx.x & 63;
#pragma unroll
    for (int co = 0; co < 16; ++co) {
      const int c = co * 4 + c4;
      tile[x][c] = (f16)feat[((size_t)(b * 64 + c) * NH + y) * NW + x0 + x];
    }
  }
  __syncthreads();
  {
    const int x4 = threadIdx.x >> 6, c = threadIdx.x & 63;
#pragma unroll
    for (int xo = 0; xo < 16; ++xo) {
      const int x = xo * 4 + x4;
      ft[((size_t)(b * NH + y) * NW + x0 + x) * 64 + c] = tile[x][c];
    }
  }
}

// One 256-wide layer, WEIGHT-STATIONARY, M=128, W double-buffered in chunks
// of CH=4 K16-steps. 4 waves (2/SIMD with sibling block); wave w owns output
// cols [w*64, w*64+64). K-loop: 4 ds_read_b128 (B, next ks, ladder
// lgkmcnt(4)) + 8 MFMA; W chunk c+1 issued at top of chunk c (vmcnt-hidden).
// NO barriers in loop. acc[4][2] f32x16. In-place act epilogue after one
// barrier. Caller must __syncthreads() after return.
template<int K>
__device__ __forceinline__ void dense_layer(const f16* __restrict__ Wt,
                                            const float* __restrict__ bias,
                                            char* actc, int w, int l) {
  constexpr int NK = K / 16;
  constexpr int CH = 4;
  const int lo = l & 31, hi = l >> 5;
  const f16* wsrc = Wt + (size_t)(w * 64 + lo) * K + hi * 8;

  f32x16 acc[4][2];
#pragma unroll
  for (int nt = 0; nt < 2; ++nt) {
    f32x16 ci;
#pragma unroll
    for (int g = 0; g < 4; ++g) {
      const float4 b4 = *(const float4*)(bias + w * 64 + nt * 32 + 8 * g + 4 * hi);
      ci[4 * g + 0] = b4.x; ci[4 * g + 1] = b4.y; ci[4 * g + 2] = b4.z; ci[4 * g + 3] = b4.w;
    }
#pragma unroll
    for (int mt = 0; mt < 4; ++mt) acc[mt][nt] = ci;
  }

  f16x8 WA[CH][2], WB[CH][2];
#pragma unroll
  for (int kk = 0; kk < CH; ++kk) {          // preload chunk 0
    if (kk < NK) {
      WA[kk][0] = *(const f16x8*)(wsrc + 0 * 32 * K + kk * 16);
      WA[kk][1] = *(const f16x8*)(wsrc + (size_t)1 * 32 * K + kk * 16);
    }
  }

  f16x8 Bb[2][4];
#pragma unroll
  for (int mt = 0; mt < 4; ++mt)   // prologue: B reads for ks=0
    Bb[0][mt] = *(const f16x8*)(actc + act_off(mt * 32 + lo, hi * 16));

#pragma unroll
  for (int c = 0; c < NK; c += CH) {
    f16x8 (*Wcur)[2] = ((c / CH) & 1) ? WB : WA;   // compile-time after unroll
    f16x8 (*Wnxt)[2] = ((c / CH) & 1) ? WA : WB;
    if (c + CH < NK) {                              // issue next chunk early
#pragma unroll
      for (int kk = 0; kk < CH; ++kk) {
        if (c + CH + kk < NK) {
          Wnxt[kk][0] = *(const f16x8*)(wsrc + 0 * 32 * K + (c + CH + kk) * 16);
          Wnxt[kk][1] = *(const f16x8*)(wsrc + (size_t)1 * 32 * K + (c + CH + kk) * 16);
        }
      }
    }
#pragma unroll
    for (int kk = 0; kk < CH; ++kk) {
      const int ks = c + kk;
      if (ks >= NK) continue;
      if (ks + 1 < NK) {             // issue next-ks B reads, ladder-wait
#pragma unroll
        for (int mt = 0; mt < 4; ++mt)
          Bb[(ks + 1) & 1][mt] =
              *(const f16x8*)(actc + act_off(mt * 32 + lo, (ks + 1) * 32 + hi * 16));
        asm volatile("s_waitcnt lgkmcnt(4)" ::: "memory");
      } else {
        asm volatile("s_waitcnt lgkmcnt(0)" ::: "memory");
      }
      __builtin_amdgcn_sched_barrier(0);  // rule #18: MFMAs stay below waitcnt

      __builtin_amdgcn_s_setprio(1);
#pragma unroll
      for (int mt = 0; mt < 4; ++mt) {
        acc[mt][0] = __builtin_amdgcn_mfma_f32_32x32x16_f16(Wcur[kk][0], Bb[ks & 1][mt], acc[mt][0], 0, 0, 0);
        acc[mt][1] = __builtin_amdgcn_mfma_f32_32x32x16_f16(Wcur[kk][1], Bb[ks & 1][mt], acc[mt][1], 0, 0, 0);
      }
      __builtin_amdgcn_s_setprio(0);
    }
  }

  __syncthreads();   // all waves done READING act -> in-place write safe

#pragma unroll
  for (int mt = 0; mt < 4; ++mt)
#pragma unroll
    for (int nt = 0; nt < 2; ++nt)
#pragma unroll
      for (int g = 0; g < 4; ++g) {
        f16x4v o;
        o[0] = (f16)fmaxf(acc[mt][nt][4 * g + 0], 0.f);
        o[1] = (f16)fmaxf(acc[mt][nt][4 * g + 1], 0.f);
        o[2] = (f16)fmaxf(acc[mt][nt][4 * g + 2], 0.f);
        o[3] = (f16)fmaxf(acc[mt][nt][4 * g + 3], 0.f);
        const int row = mt * 32 + lo;
        const int colB = w * 128 + nt * 64 + 16 * g + 8 * hi;
        *(f16x4v*)(actc + act_off(row, colB)) = o;
      }
}

template<bool USE_FT>
__global__ __launch_bounds__(256, 2) void inr2d_mfma(
    const float* __restrict__ feat, const f16* __restrict__ ft,
    const float* __restrict__ b0, const float* __restrict__ b1,
    const float* __restrict__ b2, const float* __restrict__ b3,
    const f16* __restrict__ ws, float* __restrict__ out)
{
  __shared__ f16 act[MROWS * 256];     // 64 KB, swizzled
  __shared__ f16 pred_s[MROWS][4];     // 1 KB  -> 2 blocks/CU

  char* actc = (char*)act;
  const int t = threadIdx.x;
  // XCD-chunked swizzle (8192 = 8*1024 -> bijective)
  const int blk = ((blockIdx.x & 7) << 10) | (blockIdx.x >> 3);

  // ---------- phase 0: build 128 input rows (2 threads per row) ----------
  {
    const int r = t >> 1, sub = t & 1;
    const int pix = r >> 2, e = r & 3;
    const int gp = blk * PIXB + pix;
    const int b = gp >> 16, rem = gp & 65535;
    const int oy = rem >> 8, ox = rem & 255;

    const float cy = (2.0f * oy + 1.0f) / (float)TH - 1.0f;
    const float cx = (2.0f * ox + 1.0f) / (float)TW - 1.0f;
    const float vx = (e & 2) ? 1.0f : -1.0f;
    const float vy = (e & 1) ? 1.0f : -1.0f;
    const float rr = 1.0f / (float)NH;

    float c0 = fminf(fmaxf(cy + vx * rr + 1e-6f, -1.0f + 1e-6f), 1.0f - 1e-6f);
    float c1 = fminf(fmaxf(cx + vy * rr + 1e-6f, -1.0f + 1e-6f), 1.0f - 1e-6f);

    const float ix = (c1 + 1.0f) * 0.5f * (float)(NW - 1);
    const float iy = (c0 + 1.0f) * 0.5f * (float)(NH - 1);
    const float x0f = floorf(ix), y0f = floorf(iy);
    int x0 = (int)x0f; x0 = max(0, min(x0, NW - 1));
    int x1 = min(x0 + 1, NW - 1);
    int y0 = (int)y0f; y0 = max(0, min(y0, NH - 1));
    int y1 = min(y0 + 1, NH - 1);
    const float wx1 = ix - x0f, wx0 = 1.0f - wx1;
    const float wy1 = iy - y0f, wy0 = 1.0f - wy1;
    const float w00 = wy0 * wx0, w01 = wy0 * wx1, w10 = wy1 * wx0, w11 = wy1 * wx1;

    if (USE_FT) {
      const f16 h00 = (f16)w00, h01 = (f16)w01, h10 = (f16)w10, h11 = (f16)w11;
      const f16* fb = ft + (size_t)b * (NH * NW * 64);
      const f16* r00 = fb + (size_t)(y0 * NW + x0) * 64 + sub * 32;
      const f16* r01 = fb + (size_t)(y0 * NW + x1) * 64 + sub * 32;
      const f16* r10 = fb + (size_t)(y1 * NW + x0) * 64 + sub * 32;
      const f16* r11 = fb + (size_t)(y1 * NW + x1) * 64 + sub * 32;
#pragma unroll
      for (int h = 0; h < 4; ++h) {
        const f16x8 a00 = *(const f16x8*)(r00 + h * 8);
        const f16x8 a01 = *(const f16x8*)(r01 + h * 8);
        const f16x8 a10 = *(const f16x8*)(r10 + h * 8);
        const f16x8 a11 = *(const f16x8*)(r11 + h * 8);
        f16x8 o = a00 * h00 + a01 * h01 + a10 * h10 + a11 * h11;  // v_pk_* f16
        *(f16x8*)(actc + act_off(r, 64 * sub + 16 * h)) = o;
      }
    } else {
      const float* fb = feat + (size_t)b * 64 * NH * NW;
      const int i00 = y0 * NW + x0, i01 = y0 * NW + x1;
      const int i10 = y1 * NW + x0, i11 = y1 * NW + x1;
#pragma unroll
      for (int i = 0; i < 32; ++i) {
        const int c = sub * 32 + i;
        const float* fc = fb + (size_t)c * (NH * NW);
        const float v = w00 * fc[i00] + w01 * fc[i01] + w10 * fc[i10] + w11 * fc[i11];
        *(f16*)(actc + act_off(r, 2 * c)) = (f16)v;
      }
    }
    if (sub == 0) {
      const float qy = -1.0f + 1.0f / NH + (2.0f / NH) * (wy0 * (float)y0 + wy1 * (float)y1);
      const float qx = -1.0f + 1.0f / NW + (2.0f / NW) * (wx0 * (float)x0 + wx1 * (float)x1);
      const float rely = (cy - qy) * (float)NH;
      const float relx = (cx - qx) * (float)NW;
      *(f16*)(actc + act_off(r, 2 * 64)) = (f16)rely;
      *(f16*)(actc + act_off(r, 2 * 65)) = (f16)relx;
      if (USE_FT) {
        const f16* py = ws + OFF_PE + (size_t)oy * 8;
        const f16* px = ws + OFF_PE + 2048 + (size_t)ox * 8;
#pragma unroll
        for (int j = 0; j < 8; ++j) {
          *(f16*)(actc + act_off(r, 2 * (66 + j))) = py[j];
          *(f16*)(actc + act_off(r, 2 * (74 + j))) = px[j];
        }
      } else {
#pragma unroll
        for (int ll = 0; ll < 4; ++ll) {
          const float f = (float)(1 << ll) * (float)M_PI;
          *(f16*)(actc + act_off(r, 2 * (66 + ll))) = (f16)sinf(cy * f);
          *(f16*)(actc + act_off(r, 2 * (70 + ll))) = (f16)cosf(cy * f);
          *(f16*)(actc + act_off(r, 2 * (74 + ll))) = (f16)sinf(cx * f);
          *(f16*)(actc + act_off(r, 2 * (78 + ll))) = (f16)cosf(cx * f);
        }
      }
      *(f16*)(actc + act_off(r, 2 * 82)) = (f16)1.0f;   // rel_cell = 1.0
      *(f16*)(actc + act_off(r, 2 * 83)) = (f16)1.0f;
#pragma unroll
      for (int z = 84; z < K0; ++z) *(f16*)(actc + act_off(r, 2 * z)) = (f16)0.f;
    }
  }
  __syncthreads();

  const int w = t >> 6, l = t & 63;

  dense_layer<K0 >(ws,          b0, actc, w, l);
  __syncthreads();
  dense_layer<256>(ws + OFF_W1, b1, actc, w, l);
  __syncthreads();
  dense_layer<256>(ws + OFF_W2, b2, actc, w, l);
  __syncthreads();

  // ---------- layer 3: 256 -> 3 (wave w: rows w*32 .. w*32+31) ----------
  {
    const int nl = l & 15, kq = l >> 4;
    const f16* Abase = ws + OFF_W3 + nl * 256 + kq * 8;
#pragma unroll
    for (int p = 0; p < 2; ++p) {
      const int row = w * 32 + p * 16 + nl;
      f32x4 acc = {0.f, 0.f, 0.f, 0.f};
#pragma unroll
      for (int ks = 0; ks < 8; ++ks) {
        f16x8 a = *(const f16x8*)(Abase + ks * 32);
        f16x8 b = *(const f16x8*)(actc + act_off(row, 64 * ks + 16 * kq));
        acc = __builtin_amdgcn_mfma_f32_16x16x32_f16(a, b, acc, 0, 0, 0);
      }
      if (l < 16) {
        f16x4v pr;
        pr[0] = (f16)(acc[0] + b3[0]); pr[1] = (f16)(acc[1] + b3[1]);
        pr[2] = (f16)(acc[2] + b3[2]); pr[3] = (f16)0.f;
        *(f16x4v*)(&pred_s[w * 32 + p * 16 + l][0]) = pr;
      }
    }
  }
  __syncthreads();

  // ---------- ensemble combine (areas recomputed analytically) ----------
  if (t < PIXB * 3) {
    const int pix = t / 3, o = t - pix * 3;
    const int gp = blk * PIXB + pix;
    const int b = gp >> 16, rem = gp & 65535;
    const int oy = rem >> 8, ox = rem & 255;
    const float cy = (2.0f * oy + 1.0f) / (float)TH - 1.0f;
    const float cx = (2.0f * ox + 1.0f) / (float)TW - 1.0f;
    const float rr = 1.0f / (float)NH;
    float ar[4];
#pragma unroll
    for (int e = 0; e < 4; ++e) {
      const float vx = (e & 2) ? 1.0f : -1.0f;
      const float vy = (e & 1) ? 1.0f : -1.0f;
      float c0 = fminf(fmaxf(cy + vx * rr + 1e-6f, -1.0f + 1e-6f), 1.0f - 1e-6f);
      float c1 = fminf(fmaxf(cx + vy * rr + 1e-6f, -1.0f + 1e-6f), 1.0f - 1e-6f);
      const float ix = (c1 + 1.0f) * 0.5f * (float)(NW - 1);
      const float iy = (c0 + 1.0f) * 0.5f * (float)(NH - 1);
      const float x0f = floorf(ix), y0f = floorf(iy);
      int x0 = (int)x0f; x0 = max(0, min(x0, NW - 1));
      int x1 = min(x0 + 1, NW - 1);
      int y0 = (int)y0f; y0 = max(0, min(y0, NH - 1));
      int y1 = min(y0 + 1, NH - 1);
      const float wx1 = ix - x0f, wx0 = 1.0f - wx1;
      const float wy1 = iy - y0f, wy0 = 1.0f - wy1;
      const float qy = -1.0f + 1.0f / NH + (2.0f / NH) * (wy0 * (float)y0 + wy1 * (float)y1);
      const float qx = -1.0f + 1.0f / NW + (2.0f / NW) * (wx0 * (float)x0 + wx1 * (float)x1);
      const float rely = (cy - qy) * (float)NH;
      const float relx = (cx - qx) * (float)NW;
      ar[e] = fabsf(rely * relx) + 1e-9f;
    }
    const int r0 = pix * 4;
    const float tot = ar[0] + ar[1] + ar[2] + ar[3];
    const float v = (float)pred_s[r0][o] * ar[3] + (float)pred_s[r0 + 1][o] * ar[2] +
                    (float)pred_s[r0 + 2][o] * ar[1] + (float)pred_s[r0 + 3][o] * ar[0];
    out[(((size_t)b * 3 + o) << 16) + (oy << 8) + ox] = v / tot;
  }
}

extern "C" void kernel_launch(void* const* d_in, const int* in_sizes, int n_in,
                              void* d_out, int out_size, void* d_ws, size_t ws_size,
                              hipStream_t stream) {
  const float* feat = (const float*)d_in[0];
  const float* w0 = (const float*)d_in[1];
  const float* b0 = (const float*)d_in[2];
  const float* w1 = (const float*)d_in[3];
  const float* b1 = (const float*)d_in[4];
  const float* w2 = (const float*)d_in[5];
  const float* b2 = (const float*)d_in[6];
  const float* w3 = (const float*)d_in[7];
  const float* b3 = (const float*)d_in[8];
  float* out = (float*)d_out;
  f16* ws = (f16*)d_ws;

  cvt_weights<<<(WS_W_ELEMS + 255) / 256, 256, 0, stream>>>(w0, w1, w2, w3, ws);

  const int blocks = (NB * TH * TW) / PIXB;  // 8192
  const bool use_ft = ws_size >= (size_t)(WS_W_ELEMS + FT_ELEMS) * sizeof(f16);
  if (use_ft) {
    f16* ft = ws + WS_W_ELEMS;
    transpose_feat<<<NB * NH * (NW / 64), 256, 0, stream>>>(feat, ft);
    inr2d_mfma<true><<<blocks, 256, 0, stream>>>(feat, ft, b0, b1, b2, b3, ws, out);
  } else {
    inr2d_mfma<false><<<blocks, 256, 0, stream>>>(feat, nullptr, b0, b1, b2, b3, ws, out);
  }
}